// Round 13
// baseline (122.191 us; speedup 1.0000x reference)
//
#include <hip/hip_runtime.h>
#include <hip/hip_bf16.h>
#include <hip/hip_fp16.h>

typedef unsigned int u32;
typedef unsigned short u16;
typedef __attribute__((ext_vector_type(8))) short short8;
typedef __attribute__((ext_vector_type(4))) float f32x4;

#define B_DIM 256
#define L_DIM 512
#define A_DIM 2048
#define W_DIM 64

__device__ __forceinline__ u32 fenc(float f){ u32 u=__float_as_uint(f); return (u>>31)? ~u : (u|0x80000000u); }
__device__ __forceinline__ float fdec(u32 k){ return (k>>31)? __uint_as_float(k&0x7FFFFFFFu) : __uint_as_float(~k); }
__device__ __forceinline__ u16 f2bf(float f){
  u32 u=__float_as_uint(f);
  u32 r=(u + 0x7FFFu + ((u>>16)&1u))>>16;
  return (u16)r;
}
__device__ __forceinline__ float bf2f(u16 b){ return __uint_as_float((u32)b << 16); }
__device__ __forceinline__ u16 f2h(float f){ _Float16 h = (_Float16)f; return __builtin_bit_cast(u16, h); }
__device__ __forceinline__ float h2f(u16 b){ _Float16 h = __builtin_bit_cast(_Float16, b); return (float)h; }

__device__ __forceinline__ void cvt_seg(const float* __restrict__ src, u16* __restrict__ dst, int n, int tid, int stride){
  for (int i = tid*4; i < n; i += stride){
    float4 v = *(const float4*)(src + i);
    ushort4 o;
    o.x = f2bf(v.x); o.y = f2bf(v.y); o.z = f2bf(v.z); o.w = f2bf(v.w);
    *(ushort4*)(dst + i) = o;
  }
}

// ---------------------------------------------------------------------------
// cvt_all_q: blocks 0..31 compute Q = zc @ Wq^T from raw f32; blocks 32..
// convert zw/Wk/Wv/Wo. (round-8 verbatim)
// ---------------------------------------------------------------------------
__global__ __launch_bounds__(256) void cvt_all_q(
    const float* __restrict__ zc, const float* __restrict__ Wq, float* __restrict__ Qf,
    const float* zw, u16* Zb,
    const float* s3, u16* d3, int n3,
    const float* s4, u16* d4, int n4,
    const float* s5, u16* d5, int n5,
    u32* menc)
{
  __shared__ u16 As[128*32];
  __shared__ u16 Bs[128*32];
  if (blockIdx.x == 0 && threadIdx.x < W_DIM) menc[threadIdx.x] = 0;

  if (blockIdx.x < 32){
    const int t = threadIdx.x;
    const int lane = t & 63;
    const int wave = t >> 6;
    const int wm = wave >> 1, wn = wave & 1;
    const int m0 = (blockIdx.x >> 4) * 128;
    const int n0 = (blockIdx.x & 15) * 128;

    f32x4 acc[4][4];
    #pragma unroll
    for (int i=0;i<4;++i)
      #pragma unroll
      for (int j=0;j<4;++j) acc[i][j] = (f32x4)0.f;

    const int r0 = t >> 2;
    const int lc8 = ((t&3) ^ ((t>>3)&3)) * 8;

    for (int kt = 0; kt < 16; ++kt){
      const int k0 = kt << 5;
      #pragma unroll
      for (int i = 0; i < 2; ++i){
        const float* ga = zc + (size_t)(m0 + i*64 + r0)*L_DIM + k0 + lc8;
        const float* gb = Wq + (size_t)(n0 + i*64 + r0)*L_DIM + k0 + lc8;
        float4 a0 = *(const float4*)ga, a1 = *(const float4*)(ga+4);
        float4 b0 = *(const float4*)gb, b1 = *(const float4*)(gb+4);
        short8 sa, sb;
        sa[0]=(short)f2bf(a0.x); sa[1]=(short)f2bf(a0.y); sa[2]=(short)f2bf(a0.z); sa[3]=(short)f2bf(a0.w);
        sa[4]=(short)f2bf(a1.x); sa[5]=(short)f2bf(a1.y); sa[6]=(short)f2bf(a1.z); sa[7]=(short)f2bf(a1.w);
        sb[0]=(short)f2bf(b0.x); sb[1]=(short)f2bf(b0.y); sb[2]=(short)f2bf(b0.z); sb[3]=(short)f2bf(b0.w);
        sb[4]=(short)f2bf(b1.x); sb[5]=(short)f2bf(b1.y); sb[6]=(short)f2bf(b1.z); sb[7]=(short)f2bf(b1.w);
        *(short8*)(As + i*2048 + t*8) = sa;
        *(short8*)(Bs + i*2048 + t*8) = sb;
      }
      __syncthreads();
      short8 af[4], bf[4];
      const int fr = lane & 15;
      const int k = lane >> 4;
      #pragma unroll
      for (int i=0;i<4;++i){
        const int rowA = wm*64 + i*16 + fr;
        const int rowB = wn*64 + i*16 + fr;
        af[i] = *(const short8*)(As + rowA*32 + (k ^ ((rowA>>1)&3))*8);
        bf[i] = *(const short8*)(Bs + rowB*32 + (k ^ ((rowB>>1)&3))*8);
      }
      #pragma unroll
      for (int i=0;i<4;++i)
        #pragma unroll
        for (int j=0;j<4;++j)
          acc[i][j] = __builtin_amdgcn_mfma_f32_16x16x32_bf16(af[i], bf[j], acc[i][j], 0, 0, 0);
      __syncthreads();
    }

    #pragma unroll
    for (int i=0;i<4;++i){
      const int grow_base = m0 + wm*64 + i*16 + ((lane>>4)<<2);
      #pragma unroll
      for (int j=0;j<4;++j){
        const int gcol = n0 + wn*64 + j*16 + (lane & 15);
        #pragma unroll
        for (int r=0;r<4;++r)
          Qf[(size_t)(grow_base + r)*A_DIM + gcol] = acc[i][j][r];
      }
    }
  } else {
    const int tid = (blockIdx.x - 32)*256 + threadIdx.x;
    const int stride = (gridDim.x - 32)*256*4;
    cvt_seg(zw, Zb, W_DIM*B_DIM*L_DIM, tid, stride);
    cvt_seg(s3,d3,n3,tid,stride);
    cvt_seg(s4,d4,n4,tid,stride);
    cvt_seg(s5,d5,n5,tid,stride);
  }
}

// ---------------------------------------------------------------------------
// 16-wave, 2-slot (64 KiB) K-loop core -> 2 blocks/CU co-resident.
// Per step s: {vmcnt(2) [data s landed; s=15: 0]; barrier; read slot s&1;
// 16 MFMA; barrier2; stage data(s+2) -> slot s&1}.
// Stage-at-bottom after barrier2: all waves finished reading slot s -> slot
// reuse is race-free. vmcnt(2) at step s+1 = data(s+1) retired (in-flight:
// data s+1 [oldest 2] + data s+2 [newest 2]).
// ---------------------------------------------------------------------------
#define CORE16B(STAGE_FN)                                                        \
  STAGE_FN(0); STAGE_FN(1); STAGE_FN(2); STAGE_FN(3);                            \
  _Pragma("unroll")                                                              \
  for (int s = 0; s < 16; ++s){                                                  \
    if (s < 15) asm volatile("s_waitcnt vmcnt(2)" ::: "memory");                 \
    else        asm volatile("s_waitcnt vmcnt(0)" ::: "memory");                 \
    __builtin_amdgcn_s_barrier();                                                \
    asm volatile("" ::: "memory");                                               \
    const u16* SA = &sl[s & 1][0][0];                                            \
    const u16* SB = &sl[s & 1][1][0];                                            \
    short8 af[4], bf[4];                                                         \
    _Pragma("unroll")                                                            \
    for (int i=0;i<4;++i)                                                        \
      af[i] = *(const short8*)(SA + (wm*64 + i*16 + fr)*32 + cx8);               \
    _Pragma("unroll")                                                            \
    for (int j=0;j<4;++j)                                                        \
      bf[j] = *(const short8*)(SB + (wn*64 + j*16 + fr)*32 + cx8);               \
    __builtin_amdgcn_s_setprio(1);                                               \
    _Pragma("unroll")                                                            \
    for (int i=0;i<4;++i)                                                        \
      _Pragma("unroll")                                                          \
      for (int j=0;j<4;++j)                                                      \
        acc[i][j] = __builtin_amdgcn_mfma_f32_16x16x32_bf16(af[i], bf[j], acc[i][j], 0, 0, 0); \
    __builtin_amdgcn_s_setprio(0);                                               \
    if (s + 2 < 16){                                                             \
      __builtin_amdgcn_s_barrier();                                              \
      asm volatile("" ::: "memory");                                             \
      STAGE_FN(2*(s+2)); STAGE_FN(2*(s+2)+1);                                    \
    }                                                                            \
  }

// ---------------------------------------------------------------------------
// K GEMM: 16-wave 256x256, 64 KiB LDS, stores f16 K + per-w (row/256) max.
// ---------------------------------------------------------------------------
__global__ __launch_bounds__(1024, 4) void gemm8k(
    const u16* __restrict__ Ab, const u16* __restrict__ Bb,
    u16* __restrict__ Cu, u32* __restrict__ menc)
{
  __shared__ u16 sl[2][2][256*32];   // 64 KiB
  __shared__ float wred[16];

  const int t = threadIdx.x;
  const int lane = t & 63;
  const int wv = t >> 6;             // 0..15
  const int wm = wv >> 2;            // 0..3
  const int wn = wv & 3;             // 0..3

  const int id = blockIdx.x + gridDim.x*blockIdx.y;
  const int nwg = gridDim.x*gridDim.y;
  const int chunk = nwg >> 3;
  const int swz = (id & 7)*chunk + (id >> 3);
  const int bx = swz % gridDim.x;
  const int by = swz / gridDim.x;
  const int m0 = by*256, n0 = bx*256;
  const int Kd = L_DIM;

  f32x4 acc[4][4];
  #pragma unroll
  for (int i=0;i<4;++i)
    #pragma unroll
    for (int j=0;j<4;++j) acc[i][j] = (f32x4)0.f;

  const int cg = ((t&3) ^ ((t>>3)&3)) * 8;   // staging chunk (row = t>>2)
  const int r0 = t >> 2;                      // 0..255
  const int fr = lane & 15;
  const int cx8 = ((lane>>4) ^ ((fr>>1)&3)) * 8;

  auto STAGE = [&](int u){
    const u16* src = (u & 1) ? Bb : Ab;
    const int base = (u & 1) ? n0 : m0;
    const int su = u >> 1;
    u16* dst0 = &sl[su & 1][u & 1][t*8];
    const u16* g0 = src + (size_t)(base + r0)*Kd + su*32 + cg;
    __builtin_amdgcn_global_load_lds((const __attribute__((address_space(1))) u32*)g0,
        (__attribute__((address_space(3))) u32*)dst0, 16, 0, 0);
  };

  CORE16B(STAGE)

  float vmax = -3.4e38f;
  #pragma unroll
  for (int i=0;i<4;++i){
    const int grow = m0 + wm*64 + i*16 + ((lane>>4)<<2);
    #pragma unroll
    for (int j=0;j<4;++j){
      const int gcol = n0 + wn*64 + j*16 + fr;
      #pragma unroll
      for (int r=0;r<4;++r){
        float v = acc[i][j][r];
        Cu[(size_t)(grow + r)*A_DIM + gcol] = f2h(v);
        vmax = fmaxf(vmax, v);
      }
    }
  }
  #pragma unroll
  for (int off=32; off; off>>=1) vmax = fmaxf(vmax, __shfl_xor(vmax, off));
  if (lane == 0) wred[wv] = vmax;
  __syncthreads();
  if (t == 0){
    float m = wred[0];
    #pragma unroll
    for (int i=1;i<16;++i) m = fmaxf(m, wred[i]);
    atomicMax(menc + (m0 >> 8), fenc(m));
  }
}

// ---------------------------------------------------------------------------
// Fused V-GEMM + exp-reduce + gate, 16-wave, 64 KiB LDS.
// Block = 4 b-rows x 64 w x 256 a-cols; A-tile row r -> Zb row
// (r>>2)*256 + b0 + (r&3). Epilogue: direct-global Kh reads, 4-way wm
// partial exchange via dead sl. (round-12 epilogue verbatim)
// ---------------------------------------------------------------------------
__global__ __launch_bounds__(1024, 4) void vfused_gate(
    const u16* __restrict__ Zb, const u16* __restrict__ Wvb,
    const u16* __restrict__ Kh, const u32* __restrict__ menc,
    const float* __restrict__ Qf, u16* __restrict__ g)
{
  __shared__ u16 sl[2][2][256*32];   // 64 KiB
  __shared__ float ms[W_DIM];

  const int t = threadIdx.x;
  const int lane = t & 63;
  const int wv = t >> 6;
  const int wm = wv >> 2;
  const int wn = wv & 3;

  if (t < W_DIM) ms[t] = fdec(menc[t]);

  const int id = blockIdx.x;
  const int swz = (id & 7)*64 + (id >> 3);   // XCD-aware bijective, nwg=512
  const int at = swz & 7;
  const int bt = swz >> 3;
  const int b0 = bt*4, n0 = at*256;

  f32x4 acc[4][4];
  #pragma unroll
  for (int i=0;i<4;++i)
    #pragma unroll
    for (int j=0;j<4;++j) acc[i][j] = (f32x4)0.f;

  const int cg = ((t&3) ^ ((t>>3)&3)) * 8;
  const int r0 = t >> 2;                      // 0..255
  const int fr = lane & 15;
  const int cx8 = ((lane>>4) ^ ((fr>>1)&3)) * 8;

  const u16* pA = Zb  + (size_t)(((r0>>2)<<8) + b0 + (r0&3))*L_DIM + cg;
  const u16* pB = Wvb + (size_t)(n0 + r0)*L_DIM + cg;

  auto STAGE = [&](int u){
    const int su = u >> 1;
    u16* dst0 = &sl[su & 1][u & 1][t*8];
    const u16* g0 = ((u & 1) ? pB : pA) + su*32;
    __builtin_amdgcn_global_load_lds((const __attribute__((address_space(1))) u32*)g0,
        (__attribute__((address_space(3))) u32*)dst0, 16, 0, 0);
  };

  CORE16B(STAGE)

  // ---- epilogue: exp(Kh - m_w) * V, reduce over w, fused gate ----
  float nm[4][4], dn[4][4];
  #pragma unroll
  for (int j=0;j<4;++j)
    #pragma unroll
    for (int r=0;r<4;++r){ nm[j][r]=0.f; dn[j][r]=0.f; }

  #pragma unroll
  for (int i=0;i<4;++i){
    const int w = wm*16 + i*4 + (lane>>4);
    const float mw = ms[w];
    #pragma unroll
    for (int j=0;j<4;++j){
      const u16* kp = Kh + (size_t)(w*256 + b0)*A_DIM + n0 + wn*64 + j*16 + fr;
      #pragma unroll
      for (int r=0;r<4;++r){
        float e = __expf(h2f(kp[(size_t)r*A_DIM]) - mw);
        nm[j][r] += e * acc[i][j][r];
        dn[j][r] += e;
      }
    }
  }
  #pragma unroll
  for (int j=0;j<4;++j)
    #pragma unroll
    for (int r=0;r<4;++r){
      nm[j][r] += __shfl_xor(nm[j][r], 16);
      nm[j][r] += __shfl_xor(nm[j][r], 32);
      dn[j][r] += __shfl_xor(dn[j][r], 16);
      dn[j][r] += __shfl_xor(dn[j][r], 32);
    }

  __syncthreads();                      // K-loop reads done -> reuse sl
  float* pnm = (float*)&sl[0][0][0];    // [16][256] (wm*4+r, col)
  float* pdn = pnm + 4096;              // [16][256]
  if (lane < 16){
    #pragma unroll
    for (int j=0;j<4;++j)
      #pragma unroll
      for (int r=0;r<4;++r){
        const int col = wn*64 + j*16 + fr;
        pnm[(wm*4 + r)*256 + col] = nm[j][r];
        pdn[(wm*4 + r)*256 + col] = dn[j][r];
      }
  }
  __syncthreads();
  if (wm == 0 && lane < 16){
    #pragma unroll
    for (int j=0;j<4;++j)
      #pragma unroll
      for (int r=0;r<4;++r){
        const int col = wn*64 + j*16 + fr;
        float nsum = pnm[r*256 + col] + pnm[(4+r)*256 + col]
                   + pnm[(8+r)*256 + col] + pnm[(12+r)*256 + col];
        float dsum = pdn[r*256 + col] + pdn[(4+r)*256 + col]
                   + pdn[(8+r)*256 + col] + pdn[(12+r)*256 + col];
        const size_t o = (size_t)(b0 + r)*A_DIM + n0 + col;
        const float q = Qf[o];
        g[o] = f2bf(nsum / (1e-8f + dsum) / (1.f + __expf(-q)));
      }
  }
}

// ---------------------------------------------------------------------------
// Split-K out GEMM (round-10 verbatim).
// ---------------------------------------------------------------------------
__global__ __launch_bounds__(256) void gemm_out_sk(
    const u16* __restrict__ Ab, const u16* __restrict__ Bb,
    float* __restrict__ Pout)
{
  __shared__ u16 As[128*32];
  __shared__ u16 Bs[128*32];

  const int t = threadIdx.x;
  const int lane = t & 63;
  const int wave = t >> 6;
  const int wm = wave >> 1, wn = wave & 1;
  const int m0 = blockIdx.y * 128;
  const int n0 = blockIdx.x * 128;
  const int kc = blockIdx.z;
  const int Kd = A_DIM;
  float* Cf = Pout + (size_t)kc * (B_DIM * L_DIM);

  f32x4 acc[4][4];
  #pragma unroll
  for (int i=0;i<4;++i)
    #pragma unroll
    for (int j=0;j<4;++j) acc[i][j] = (f32x4)0.f;

  const int row_in = t >> 2;
  const int cg = ((t&3) ^ ((t>>3)&3)) * 8;
  const int wbase = (t & 192) * 8;

  for (int kt = 0; kt < 8; ++kt){
    const int k0 = kc*256 + (kt << 5);
    #pragma unroll
    for (int i = 0; i < 2; ++i){
      const u16* ga = Ab + (size_t)(m0 + i*64 + row_in)*Kd + k0 + cg;
      const u16* gb = Bb + (size_t)(n0 + i*64 + row_in)*Kd + k0 + cg;
      __builtin_amdgcn_global_load_lds((const __attribute__((address_space(1))) u32*)ga,
          (__attribute__((address_space(3))) u32*)(As + i*2048 + wbase), 16, 0, 0);
      __builtin_amdgcn_global_load_lds((const __attribute__((address_space(1))) u32*)gb,
          (__attribute__((address_space(3))) u32*)(Bs + i*2048 + wbase), 16, 0, 0);
    }
    __syncthreads();
    short8 af[4], bf[4];
    const int fr = lane & 15;
    const int k = lane >> 4;
    #pragma unroll
    for (int i=0;i<4;++i){
      const int rowA = wm*64 + i*16 + fr;
      const int rowB = wn*64 + i*16 + fr;
      af[i] = *(const short8*)(As + rowA*32 + (k ^ ((rowA>>1)&3))*8);
      bf[i] = *(const short8*)(Bs + rowB*32 + (k ^ ((rowB>>1)&3))*8);
    }
    #pragma unroll
    for (int i=0;i<4;++i)
      #pragma unroll
      for (int j=0;j<4;++j)
        acc[i][j] = __builtin_amdgcn_mfma_f32_16x16x32_bf16(af[i], bf[j], acc[i][j], 0, 0, 0);
    __syncthreads();
  }

  #pragma unroll
  for (int i=0;i<4;++i){
    const int grow_base = m0 + wm*64 + i*16 + ((lane>>4)<<2);
    #pragma unroll
    for (int j=0;j<4;++j){
      const int gcol = n0 + wn*64 + j*16 + (lane & 15);
      #pragma unroll
      for (int r=0;r<4;++r)
        Cf[(size_t)(grow_base + r)*L_DIM + gcol] = acc[i][j][r];
    }
  }
}

// sum the 8 split-K partial planes -> out (f32), deterministic fixed order
__global__ __launch_bounds__(256) void reduce_sk(
    const float* __restrict__ Pout, float* __restrict__ out)
{
  const int idx = (blockIdx.x*blockDim.x + threadIdx.x) * 4;
  const int plane = B_DIM * L_DIM;
  float4 s = *(const float4*)(Pout + idx);
  #pragma unroll
  for (int kc = 1; kc < 8; ++kc){
    float4 v = *(const float4*)(Pout + (size_t)kc*plane + idx);
    s.x += v.x; s.y += v.y; s.z += v.z; s.w += v.w;
  }
  *(float4*)(out + idx) = s;
}

extern "C" void kernel_launch(void* const* d_in, const int* in_sizes, int n_in,
                              void* d_out, int out_size, void* d_ws, size_t ws_size,
                              hipStream_t stream){
  const float* zc = (const float*)d_in[0];
  const float* zw = (const float*)d_in[1];
  const float* Wq = (const float*)d_in[2];
  const float* Wk = (const float*)d_in[3];
  const float* Wv = (const float*)d_in[4];
  const float* Wo = (const float*)d_in[5];
  float* out = (float*)d_out;

  char* ws = (char*)d_ws;
  size_t off = 0;
  auto alloc = [&](size_t bytes)->void*{ void* p = ws + off; off += (bytes + 255) & ~(size_t)255; return p; };
  u16*  Zb   = (u16*) alloc((size_t)W_DIM*B_DIM*L_DIM*2);
  u16*  Wkb  = (u16*) alloc((size_t)A_DIM*L_DIM*2);
  u16*  Wvb  = (u16*) alloc((size_t)A_DIM*L_DIM*2);
  u16*  Wob  = (u16*) alloc((size_t)L_DIM*A_DIM*2);
  u16*  Kh   = (u16*) alloc((size_t)W_DIM*B_DIM*A_DIM*2);   // 67 MB f16
  float* Qf  = (float*)alloc((size_t)B_DIM*A_DIM*4);
  u16*  g    = (u16*) alloc((size_t)B_DIM*A_DIM*2);
  float* Pout= (float*)alloc((size_t)8*B_DIM*L_DIM*4);
  u32*  menc = (u32*) alloc(W_DIM*4);

  cvt_all_q<<<768, 256, 0, stream>>>(zc, Wq, Qf,
                                     zw, Zb,
                                     Wk, Wkb, A_DIM*L_DIM,
                                     Wv, Wvb, A_DIM*L_DIM,
                                     Wo, Wob, L_DIM*A_DIM,
                                     menc);

  // K (f16 + per-w max): 512 blocks x 1024 threads, 2 blocks/CU
  gemm8k<<<dim3(A_DIM/256, (W_DIM*B_DIM)/256), 1024, 0, stream>>>(Zb, Wkb, Kh, menc);

  // V-GEMM fused with exp-reduce and gating -> g (bf16)
  vfused_gate<<<512, 1024, 0, stream>>>(Zb, Wvb, Kh, menc, Qf, g);

  // out = g @ Wo^T, split-K over 8 chunks, then reduce
  gemm_out_sk<<<dim3(L_DIM/128, B_DIM/128, 8), 256, 0, stream>>>(g, Wob, Pout);
  reduce_sk<<<(B_DIM*L_DIM)/(256*4), 256, 0, stream>>>(Pout, out);
}

// Round 14
// 119.444 us; speedup vs baseline: 1.0230x; 1.0230x over previous
//
#include <hip/hip_runtime.h>
#include <hip/hip_bf16.h>
#include <hip/hip_fp16.h>

typedef unsigned int u32;
typedef unsigned short u16;
typedef __attribute__((ext_vector_type(8))) short short8;
typedef __attribute__((ext_vector_type(4))) float f32x4;

#define B_DIM 256
#define L_DIM 512
#define A_DIM 2048
#define W_DIM 64

__device__ __forceinline__ u32 fenc(float f){ u32 u=__float_as_uint(f); return (u>>31)? ~u : (u|0x80000000u); }
__device__ __forceinline__ float fdec(u32 k){ return (k>>31)? __uint_as_float(k&0x7FFFFFFFu) : __uint_as_float(~k); }
__device__ __forceinline__ u16 f2bf(float f){
  u32 u=__float_as_uint(f);
  u32 r=(u + 0x7FFFu + ((u>>16)&1u))>>16;
  return (u16)r;
}
__device__ __forceinline__ float bf2f(u16 b){ return __uint_as_float((u32)b << 16); }
__device__ __forceinline__ u16 f2h(float f){ _Float16 h = (_Float16)f; return __builtin_bit_cast(u16, h); }
__device__ __forceinline__ float h2f(u16 b){ _Float16 h = __builtin_bit_cast(_Float16, b); return (float)h; }

__device__ __forceinline__ void cvt_seg(const float* __restrict__ src, u16* __restrict__ dst, int n, int tid, int stride){
  for (int i = tid*4; i < n; i += stride){
    float4 v = *(const float4*)(src + i);
    ushort4 o;
    o.x = f2bf(v.x); o.y = f2bf(v.y); o.z = f2bf(v.z); o.w = f2bf(v.w);
    *(ushort4*)(dst + i) = o;
  }
}

// ---------------------------------------------------------------------------
// cvt_all_q: blocks 0..31 compute Q = zc @ Wq^T from raw f32; blocks 32..
// convert zw/Wk/Wv/Wo. (round-8 verbatim)
// ---------------------------------------------------------------------------
__global__ __launch_bounds__(256) void cvt_all_q(
    const float* __restrict__ zc, const float* __restrict__ Wq, float* __restrict__ Qf,
    const float* zw, u16* Zb,
    const float* s3, u16* d3, int n3,
    const float* s4, u16* d4, int n4,
    const float* s5, u16* d5, int n5,
    u32* menc)
{
  __shared__ u16 As[128*32];
  __shared__ u16 Bs[128*32];
  if (blockIdx.x == 0 && threadIdx.x < W_DIM) menc[threadIdx.x] = 0;

  if (blockIdx.x < 32){
    const int t = threadIdx.x;
    const int lane = t & 63;
    const int wave = t >> 6;
    const int wm = wave >> 1, wn = wave & 1;
    const int m0 = (blockIdx.x >> 4) * 128;
    const int n0 = (blockIdx.x & 15) * 128;

    f32x4 acc[4][4];
    #pragma unroll
    for (int i=0;i<4;++i)
      #pragma unroll
      for (int j=0;j<4;++j) acc[i][j] = (f32x4)0.f;

    const int r0 = t >> 2;
    const int lc8 = ((t&3) ^ ((t>>3)&3)) * 8;

    for (int kt = 0; kt < 16; ++kt){
      const int k0 = kt << 5;
      #pragma unroll
      for (int i = 0; i < 2; ++i){
        const float* ga = zc + (size_t)(m0 + i*64 + r0)*L_DIM + k0 + lc8;
        const float* gb = Wq + (size_t)(n0 + i*64 + r0)*L_DIM + k0 + lc8;
        float4 a0 = *(const float4*)ga, a1 = *(const float4*)(ga+4);
        float4 b0 = *(const float4*)gb, b1 = *(const float4*)(gb+4);
        short8 sa, sb;
        sa[0]=(short)f2bf(a0.x); sa[1]=(short)f2bf(a0.y); sa[2]=(short)f2bf(a0.z); sa[3]=(short)f2bf(a0.w);
        sa[4]=(short)f2bf(a1.x); sa[5]=(short)f2bf(a1.y); sa[6]=(short)f2bf(a1.z); sa[7]=(short)f2bf(a1.w);
        sb[0]=(short)f2bf(b0.x); sb[1]=(short)f2bf(b0.y); sb[2]=(short)f2bf(b0.z); sb[3]=(short)f2bf(b0.w);
        sb[4]=(short)f2bf(b1.x); sb[5]=(short)f2bf(b1.y); sb[6]=(short)f2bf(b1.z); sb[7]=(short)f2bf(b1.w);
        *(short8*)(As + i*2048 + t*8) = sa;
        *(short8*)(Bs + i*2048 + t*8) = sb;
      }
      __syncthreads();
      short8 af[4], bf[4];
      const int fr = lane & 15;
      const int k = lane >> 4;
      #pragma unroll
      for (int i=0;i<4;++i){
        const int rowA = wm*64 + i*16 + fr;
        const int rowB = wn*64 + i*16 + fr;
        af[i] = *(const short8*)(As + rowA*32 + (k ^ ((rowA>>1)&3))*8);
        bf[i] = *(const short8*)(Bs + rowB*32 + (k ^ ((rowB>>1)&3))*8);
      }
      #pragma unroll
      for (int i=0;i<4;++i)
        #pragma unroll
        for (int j=0;j<4;++j)
          acc[i][j] = __builtin_amdgcn_mfma_f32_16x16x32_bf16(af[i], bf[j], acc[i][j], 0, 0, 0);
      __syncthreads();
    }

    #pragma unroll
    for (int i=0;i<4;++i){
      const int grow_base = m0 + wm*64 + i*16 + ((lane>>4)<<2);
      #pragma unroll
      for (int j=0;j<4;++j){
        const int gcol = n0 + wn*64 + j*16 + (lane & 15);
        #pragma unroll
        for (int r=0;r<4;++r)
          Qf[(size_t)(grow_base + r)*A_DIM + gcol] = acc[i][j][r];
      }
    }
  } else {
    const int tid = (blockIdx.x - 32)*256 + threadIdx.x;
    const int stride = (gridDim.x - 32)*256*4;
    cvt_seg(zw, Zb, W_DIM*B_DIM*L_DIM, tid, stride);
    cvt_seg(s3,d3,n3,tid,stride);
    cvt_seg(s4,d4,n4,tid,stride);
    cvt_seg(s5,d5,n5,tid,stride);
  }
}

// ---------------------------------------------------------------------------
// 16-wave single-barrier K-loop core (256x256 tile, BK=32, 4-slot ring).
// Round-12 verbatim (best measured config).
// ---------------------------------------------------------------------------
#define CORE16(STAGE_FN)                                                         \
  STAGE_FN(0); STAGE_FN(1); STAGE_FN(2); STAGE_FN(3);                            \
  _Pragma("unroll")                                                              \
  for (int s = 0; s < 16; ++s){                                                  \
    if (s + 2 < 16){ STAGE_FN(2*(s+2)); STAGE_FN(2*(s+2)+1); }                   \
    if (s < 14)      asm volatile("s_waitcnt vmcnt(4)" ::: "memory");            \
    else if (s==14)  asm volatile("s_waitcnt vmcnt(2)" ::: "memory");            \
    else             asm volatile("s_waitcnt vmcnt(0)" ::: "memory");            \
    __builtin_amdgcn_s_barrier();                                                \
    asm volatile("" ::: "memory");                                               \
    const u16* SA = &sl[s & 3][0][0];                                            \
    const u16* SB = &sl[s & 3][1][0];                                            \
    short8 af[4], bf[4];                                                         \
    _Pragma("unroll")                                                            \
    for (int i=0;i<4;++i)                                                        \
      af[i] = *(const short8*)(SA + (wm*64 + i*16 + fr)*32 + cx8);               \
    _Pragma("unroll")                                                            \
    for (int j=0;j<4;++j)                                                        \
      bf[j] = *(const short8*)(SB + (wn*64 + j*16 + fr)*32 + cx8);               \
    __builtin_amdgcn_s_setprio(1);                                               \
    _Pragma("unroll")                                                            \
    for (int i=0;i<4;++i)                                                        \
      _Pragma("unroll")                                                          \
      for (int j=0;j<4;++j)                                                      \
        acc[i][j] = __builtin_amdgcn_mfma_f32_16x16x32_bf16(af[i], bf[j], acc[i][j], 0, 0, 0); \
    __builtin_amdgcn_s_setprio(0);                                               \
  }

// ---------------------------------------------------------------------------
// K GEMM: 16-wave 256x256, stores f16 K + per-w (row/256) max. (r12 verbatim)
// ---------------------------------------------------------------------------
__global__ __launch_bounds__(1024, 4) void gemm8k(
    const u16* __restrict__ Ab, const u16* __restrict__ Bb,
    u16* __restrict__ Cu, u32* __restrict__ menc)
{
  __shared__ u16 sl[4][2][256*32];   // 128 KiB
  __shared__ float wred[16];

  const int t = threadIdx.x;
  const int lane = t & 63;
  const int wv = t >> 6;             // 0..15
  const int wm = wv >> 2;            // 0..3
  const int wn = wv & 3;             // 0..3

  const int id = blockIdx.x + gridDim.x*blockIdx.y;
  const int nwg = gridDim.x*gridDim.y;
  const int chunk = nwg >> 3;
  const int swz = (id & 7)*chunk + (id >> 3);
  const int bx = swz % gridDim.x;
  const int by = swz / gridDim.x;
  const int m0 = by*256, n0 = bx*256;
  const int Kd = L_DIM;

  f32x4 acc[4][4];
  #pragma unroll
  for (int i=0;i<4;++i)
    #pragma unroll
    for (int j=0;j<4;++j) acc[i][j] = (f32x4)0.f;

  const int cg = ((t&3) ^ ((t>>3)&3)) * 8;   // staging chunk (row = t>>2)
  const int r0 = t >> 2;                      // 0..255
  const int fr = lane & 15;
  const int cx8 = ((lane>>4) ^ ((fr>>1)&3)) * 8;

  auto STAGE = [&](int u){
    const u16* src = (u & 1) ? Bb : Ab;
    const int base = (u & 1) ? n0 : m0;
    const int su = u >> 1;
    u16* dst0 = &sl[su & 3][u & 1][t*8];
    const u16* g0 = src + (size_t)(base + r0)*Kd + su*32 + cg;
    __builtin_amdgcn_global_load_lds((const __attribute__((address_space(1))) u32*)g0,
        (__attribute__((address_space(3))) u32*)dst0, 16, 0, 0);
  };

  CORE16(STAGE)

  float vmax = -3.4e38f;
  #pragma unroll
  for (int i=0;i<4;++i){
    const int grow = m0 + wm*64 + i*16 + ((lane>>4)<<2);
    #pragma unroll
    for (int j=0;j<4;++j){
      const int gcol = n0 + wn*64 + j*16 + fr;
      #pragma unroll
      for (int r=0;r<4;++r){
        float v = acc[i][j][r];
        Cu[(size_t)(grow + r)*A_DIM + gcol] = f2h(v);
        vmax = fmaxf(vmax, v);
      }
    }
  }
  #pragma unroll
  for (int off=32; off; off>>=1) vmax = fmaxf(vmax, __shfl_xor(vmax, off));
  if (lane == 0) wred[wv] = vmax;
  __syncthreads();
  if (t == 0){
    float m = wred[0];
    #pragma unroll
    for (int i=1;i<16;++i) m = fmaxf(m, wred[i]);
    atomicMax(menc + (m0 >> 8), fenc(m));
  }
}

// ---------------------------------------------------------------------------
// Fused V-GEMM + exp-reduce + gate, 16-wave. (r12 verbatim)
// Block = 4 b-rows x 64 w x 256 a-cols.
// ---------------------------------------------------------------------------
__global__ __launch_bounds__(1024, 4) void vfused_gate(
    const u16* __restrict__ Zb, const u16* __restrict__ Wvb,
    const u16* __restrict__ Kh, const u32* __restrict__ menc,
    const float* __restrict__ Qf, u16* __restrict__ g)
{
  __shared__ u16 sl[4][2][256*32];   // 128 KiB
  __shared__ float ms[W_DIM];

  const int t = threadIdx.x;
  const int lane = t & 63;
  const int wv = t >> 6;
  const int wm = wv >> 2;
  const int wn = wv & 3;

  if (t < W_DIM) ms[t] = fdec(menc[t]);

  const int id = blockIdx.x;
  const int swz = (id & 7)*64 + (id >> 3);   // XCD-aware bijective, nwg=512
  const int at = swz & 7;
  const int bt = swz >> 3;
  const int b0 = bt*4, n0 = at*256;

  f32x4 acc[4][4];
  #pragma unroll
  for (int i=0;i<4;++i)
    #pragma unroll
    for (int j=0;j<4;++j) acc[i][j] = (f32x4)0.f;

  const int cg = ((t&3) ^ ((t>>3)&3)) * 8;
  const int r0 = t >> 2;                      // 0..255
  const int fr = lane & 15;
  const int cx8 = ((lane>>4) ^ ((fr>>1)&3)) * 8;

  const u16* pA = Zb  + (size_t)(((r0>>2)<<8) + b0 + (r0&3))*L_DIM + cg;
  const u16* pB = Wvb + (size_t)(n0 + r0)*L_DIM + cg;

  auto STAGE = [&](int u){
    const int su = u >> 1;
    u16* dst0 = &sl[su & 3][u & 1][t*8];
    const u16* g0 = ((u & 1) ? pB : pA) + su*32;
    __builtin_amdgcn_global_load_lds((const __attribute__((address_space(1))) u32*)g0,
        (__attribute__((address_space(3))) u32*)dst0, 16, 0, 0);
  };

  CORE16(STAGE)

  // ---- epilogue: exp(Kh - m_w) * V, reduce over w, fused gate ----
  float nm[4][4], dn[4][4];
  #pragma unroll
  for (int j=0;j<4;++j)
    #pragma unroll
    for (int r=0;r<4;++r){ nm[j][r]=0.f; dn[j][r]=0.f; }

  #pragma unroll
  for (int i=0;i<4;++i){
    const int w = wm*16 + i*4 + (lane>>4);
    const float mw = ms[w];
    #pragma unroll
    for (int j=0;j<4;++j){
      const u16* kp = Kh + (size_t)(w*256 + b0)*A_DIM + n0 + wn*64 + j*16 + fr;
      #pragma unroll
      for (int r=0;r<4;++r){
        float e = __expf(h2f(kp[(size_t)r*A_DIM]) - mw);
        nm[j][r] += e * acc[i][j][r];
        dn[j][r] += e;
      }
    }
  }
  #pragma unroll
  for (int j=0;j<4;++j)
    #pragma unroll
    for (int r=0;r<4;++r){
      nm[j][r] += __shfl_xor(nm[j][r], 16);
      nm[j][r] += __shfl_xor(nm[j][r], 32);
      dn[j][r] += __shfl_xor(dn[j][r], 16);
      dn[j][r] += __shfl_xor(dn[j][r], 32);
    }

  __syncthreads();                      // K-loop reads done -> reuse sl
  float* pnm = (float*)&sl[0][0][0];    // [16][256] (wm*4+r, col)
  float* pdn = pnm + 4096;              // [16][256]
  if (lane < 16){
    #pragma unroll
    for (int j=0;j<4;++j)
      #pragma unroll
      for (int r=0;r<4;++r){
        const int col = wn*64 + j*16 + fr;
        pnm[(wm*4 + r)*256 + col] = nm[j][r];
        pdn[(wm*4 + r)*256 + col] = dn[j][r];
      }
  }
  __syncthreads();
  if (wm == 0 && lane < 16){
    #pragma unroll
    for (int j=0;j<4;++j)
      #pragma unroll
      for (int r=0;r<4;++r){
        const int col = wn*64 + j*16 + fr;
        float nsum = pnm[r*256 + col] + pnm[(4+r)*256 + col]
                   + pnm[(8+r)*256 + col] + pnm[(12+r)*256 + col];
        float dsum = pdn[r*256 + col] + pdn[(4+r)*256 + col]
                   + pdn[(8+r)*256 + col] + pdn[(12+r)*256 + col];
        const size_t o = (size_t)(b0 + r)*A_DIM + n0 + col;
        const float q = Qf[o];
        g[o] = f2bf(nsum / (1e-8f + dsum) / (1.f + __expf(-q)));
      }
  }
}

// ---------------------------------------------------------------------------
// Split-K out GEMM: 16 K-chunks of 128 (blockIdx.z), 4 K-steps per block,
// 128 blocks total. Writes disjoint f32 partial planes (deterministic).
// ---------------------------------------------------------------------------
__global__ __launch_bounds__(256) void gemm_out_sk(
    const u16* __restrict__ Ab, const u16* __restrict__ Bb,
    float* __restrict__ Pout)
{
  __shared__ u16 As[128*32];
  __shared__ u16 Bs[128*32];

  const int t = threadIdx.x;
  const int lane = t & 63;
  const int wave = t >> 6;
  const int wm = wave >> 1, wn = wave & 1;
  const int m0 = blockIdx.y * 128;
  const int n0 = blockIdx.x * 128;
  const int kc = blockIdx.z;
  const int Kd = A_DIM;
  float* Cf = Pout + (size_t)kc * (B_DIM * L_DIM);

  f32x4 acc[4][4];
  #pragma unroll
  for (int i=0;i<4;++i)
    #pragma unroll
    for (int j=0;j<4;++j) acc[i][j] = (f32x4)0.f;

  const int row_in = t >> 2;
  const int cg = ((t&3) ^ ((t>>3)&3)) * 8;
  const int wbase = (t & 192) * 8;

  for (int kt = 0; kt < 4; ++kt){
    const int k0 = kc*128 + (kt << 5);
    #pragma unroll
    for (int i = 0; i < 2; ++i){
      const u16* ga = Ab + (size_t)(m0 + i*64 + row_in)*Kd + k0 + cg;
      const u16* gb = Bb + (size_t)(n0 + i*64 + row_in)*Kd + k0 + cg;
      __builtin_amdgcn_global_load_lds((const __attribute__((address_space(1))) u32*)ga,
          (__attribute__((address_space(3))) u32*)(As + i*2048 + wbase), 16, 0, 0);
      __builtin_amdgcn_global_load_lds((const __attribute__((address_space(1))) u32*)gb,
          (__attribute__((address_space(3))) u32*)(Bs + i*2048 + wbase), 16, 0, 0);
    }
    __syncthreads();
    short8 af[4], bf[4];
    const int fr = lane & 15;
    const int k = lane >> 4;
    #pragma unroll
    for (int i=0;i<4;++i){
      const int rowA = wm*64 + i*16 + fr;
      const int rowB = wn*64 + i*16 + fr;
      af[i] = *(const short8*)(As + rowA*32 + (k ^ ((rowA>>1)&3))*8);
      bf[i] = *(const short8*)(Bs + rowB*32 + (k ^ ((rowB>>1)&3))*8);
    }
    #pragma unroll
    for (int i=0;i<4;++i)
      #pragma unroll
      for (int j=0;j<4;++j)
        acc[i][j] = __builtin_amdgcn_mfma_f32_16x16x32_bf16(af[i], bf[j], acc[i][j], 0, 0, 0);
    __syncthreads();
  }

  #pragma unroll
  for (int i=0;i<4;++i){
    const int grow_base = m0 + wm*64 + i*16 + ((lane>>4)<<2);
    #pragma unroll
    for (int j=0;j<4;++j){
      const int gcol = n0 + wn*64 + j*16 + (lane & 15);
      #pragma unroll
      for (int r=0;r<4;++r)
        Cf[(size_t)(grow_base + r)*L_DIM + gcol] = acc[i][j][r];
    }
  }
}

// sum the 16 split-K partial planes -> out (f32), deterministic fixed order
__global__ __launch_bounds__(256) void reduce_sk(
    const float* __restrict__ Pout, float* __restrict__ out)
{
  const int idx = (blockIdx.x*blockDim.x + threadIdx.x) * 4;
  const int plane = B_DIM * L_DIM;
  float4 s = *(const float4*)(Pout + idx);
  #pragma unroll
  for (int kc = 1; kc < 16; ++kc){
    float4 v = *(const float4*)(Pout + (size_t)kc*plane + idx);
    s.x += v.x; s.y += v.y; s.z += v.z; s.w += v.w;
  }
  *(float4*)(out + idx) = s;
}

extern "C" void kernel_launch(void* const* d_in, const int* in_sizes, int n_in,
                              void* d_out, int out_size, void* d_ws, size_t ws_size,
                              hipStream_t stream){
  const float* zc = (const float*)d_in[0];
  const float* zw = (const float*)d_in[1];
  const float* Wq = (const float*)d_in[2];
  const float* Wk = (const float*)d_in[3];
  const float* Wv = (const float*)d_in[4];
  const float* Wo = (const float*)d_in[5];
  float* out = (float*)d_out;

  char* ws = (char*)d_ws;
  size_t off = 0;
  auto alloc = [&](size_t bytes)->void*{ void* p = ws + off; off += (bytes + 255) & ~(size_t)255; return p; };
  u16*  Zb   = (u16*) alloc((size_t)W_DIM*B_DIM*L_DIM*2);
  u16*  Wkb  = (u16*) alloc((size_t)A_DIM*L_DIM*2);
  u16*  Wvb  = (u16*) alloc((size_t)A_DIM*L_DIM*2);
  u16*  Wob  = (u16*) alloc((size_t)L_DIM*A_DIM*2);
  u16*  Kh   = (u16*) alloc((size_t)W_DIM*B_DIM*A_DIM*2);   // 67 MB f16
  float* Qf  = (float*)alloc((size_t)B_DIM*A_DIM*4);
  u16*  g    = (u16*) alloc((size_t)B_DIM*A_DIM*2);
  float* Pout= (float*)alloc((size_t)16*B_DIM*L_DIM*4);     // 8.4 MB split-K partials
  u32*  menc = (u32*) alloc(W_DIM*4);

  cvt_all_q<<<768, 256, 0, stream>>>(zc, Wq, Qf,
                                     zw, Zb,
                                     Wk, Wkb, A_DIM*L_DIM,
                                     Wv, Wvb, A_DIM*L_DIM,
                                     Wo, Wob, L_DIM*A_DIM,
                                     menc);

  // K (f16 + per-w max): 512 blocks x 1024 threads (r12 config)
  gemm8k<<<dim3(A_DIM/256, (W_DIM*B_DIM)/256), 1024, 0, stream>>>(Zb, Wkb, Kh, menc);

  // V-GEMM fused with exp-reduce and gating -> g (bf16)
  vfused_gate<<<512, 1024, 0, stream>>>(Zb, Wvb, Kh, menc, Qf, g);

  // out = g @ Wo^T, split-K over 16 chunks (128 blocks), then reduce
  gemm_out_sk<<<dim3(L_DIM/128, B_DIM/128, 16), 256, 0, stream>>>(g, Wob, Pout);
  reduce_sk<<<(B_DIM*L_DIM)/(256*4), 256, 0, stream>>>(Pout, out);
}